// Round 2
// baseline (238.148 us; speedup 1.0000x reference)
//
#include <hip/hip_runtime.h>
#include <math.h>

// InteractionBlock two-phase (no output atomics):
//  K1 (interact_kernel): per-edge geometry + bessel MLP + 16x768 GEMM against
//      LDS-resident W2. Each active edge claims a slot (1 atomicAdd on a global
//      counter), links into a per-dst linked list, and writes v[3][16] (scaled)
//      + Y[9] = 57 floats to ws. ~150MB of atomic HBM traffic (R1) -> ~16MB.
//  K2 (gather_kernel): 16 threads per node walk the list, expand msg = v_l[h]*Y[m],
//      write each of the 144 outputs exactly once.
// Fallback: R1-style atomic kernel if ws_size is too small.

#define W2S 20  // LDS row stride in floats for the transposed W2 tile

// ---------------- compute kernel (phase 1) ----------------
__global__ __launch_bounds__(256, 2)
void interact_kernel(const float* __restrict__ xfeat,
                     const float* __restrict__ coords,
                     const int* __restrict__ eidx,
                     const float* __restrict__ W1g,
                     const float* __restrict__ W2g,
                     float* __restrict__ data,   // [E][64]
                     int* __restrict__ head,     // [N] init -1
                     int* __restrict__ next,     // [E]
                     int* __restrict__ ctr,      // [1] init 0
                     int E, int ntiles)
{
  __shared__ float W2s[768 * W2S];
  __shared__ float W1s[256];
  __shared__ float xss[16][16];
  __shared__ float hss[16][16];
  __shared__ unsigned char clist[256];
  __shared__ int wsum[4];
  __shared__ int slotS[16];

  const int tid = threadIdx.x;

  W1s[tid] = W1g[tid];
  for (int t = tid; t < 12288; t += 256) {
    int k = t / 768;
    int r = t - k * 768;
    int l = r >> 8;
    int rc = r & 255;
    int c = rc >> 4;
    int h = rc & 15;
    W2s[((k * 3 + l) * 16 + h) * W2S + c] = W2g[t];
  }
  __syncthreads();

  const int slot  = tid >> 4;
  const int jlane = tid & 15;
  const int wid   = tid >> 6;
  const int lane  = tid & 63;

  for (int tile = blockIdx.x; tile < ntiles; tile += gridDim.x) {
    const int ebase = tile * 256;

    int e = ebase + tid;
    bool act = false;
    if (e < E) {
      int s = eidx[e], d = eidx[E + e];
      float rx = coords[3*s]   - coords[3*d];
      float ry = coords[3*s+1] - coords[3*d+1];
      float rz = coords[3*s+2] - coords[3*d+2];
      float d2 = rx*rx + ry*ry + rz*rz;
      act = (d2 > 0.0f) && (d2 < 36.0f);
    }
    unsigned long long bm = __ballot(act);
    int pfx = __popcll(bm & ((1ull << lane) - 1ull));
    if (lane == 0) wsum[wid] = __popcll(bm);
    __syncthreads();
    int base = 0;
    #pragma unroll
    for (int w = 0; w < 4; w++) base += (w < wid) ? wsum[w] : 0;
    const int total = wsum[0] + wsum[1] + wsum[2] + wsum[3];
    if (act) clist[base + pfx] = (unsigned char)tid;
    __syncthreads();

    for (int s0 = 0; s0 < total; s0 += 16) {
      const int ci = s0 + slot;
      const bool on = ci < total;
      float Y[9];
      if (on) {
        const int ee  = ebase + (int)clist[ci];
        const int src = eidx[ee];
        const int dst = eidx[E + ee];
        float rx = coords[3*src]   - coords[3*dst];
        float ry = coords[3*src+1] - coords[3*dst+1];
        float rz = coords[3*src+2] - coords[3*dst+2];
        float dd  = sqrtf(rx*rx + ry*ry + rz*rz);
        float inv = 1.0f / dd;
        float x = rx*inv, y = ry*inv, z = rz*inv;
        const float A0 = 0.28209479177387814f;
        const float A1 = 0.48860251190291992f;
        const float A2 = 1.09254843059207907f;
        const float A3 = 0.63078313050504001f;
        Y[0] = A0;
        Y[1] = A1*x;   Y[2] = A1*y;   Y[3] = A1*z;
        Y[4] = A2*x*z; Y[5] = A2*x*y;
        Y[6] = A3*(y*y - 0.5f*(x*x + z*z));
        Y[7] = A2*y*z;
        Y[8] = 0.5f*A2*(z*z - x*x);
        float theta = 0.52359877559829887f * dd;  // pi/6 * d
        float s1 = __sinf(theta), c1 = __cosf(theta);
        float snm = 0.0f, sn = s1, bsum = 0.0f;
        #pragma unroll
        for (int k = 0; k < 16; k++) {
          bsum = fmaf(sn, W1s[k*16 + jlane], bsum);
          float sp = 2.0f*c1*sn - snm;
          snm = sn; sn = sp;
        }
        float p  = bsum * (2.30940107675850305f * inv) * 0.25f;
        float hv = 1.679177f * p / (1.0f + __expf(-p));
        hss[slot][jlane] = hv;
        xss[slot][jlane] = xfeat[src*16 + jlane];
        if (jlane == 0) {
          int s = atomicAdd(ctr, 1);
          next[s] = atomicExch(&head[dst], s);
          slotS[slot] = s;
        }
      }
      __syncthreads();
      if (on) {
        float acc[3][16];
        #pragma unroll
        for (int l = 0; l < 3; l++)
          #pragma unroll
          for (int c = 0; c < 16; c++) acc[l][c] = 0.0f;
        #pragma unroll
        for (int k = 0; k < 16; k++) {
          const float hk = hss[slot][k];
          #pragma unroll
          for (int l = 0; l < 3; l++) {
            const float* wr = &W2s[((k*3 + l)*16 + jlane) * W2S];
            #pragma unroll
            for (int c = 0; c < 16; c++)
              acc[l][c] = fmaf(hk, wr[c], acc[l][c]);
          }
        }
        float v0 = 0.f, v1 = 0.f, v2 = 0.f;
        #pragma unroll
        for (int c = 0; c < 16; c++) {
          const float xc = xss[slot][c];
          v0 = fmaf(xc, acc[0][c], v0);
          v1 = fmaf(xc, acc[1][c], v1);
          v2 = fmaf(xc, acc[2][c], v2);
        }
        const float sc = 0.00390625f;  // 1/256
        const int s = slotS[slot];
        float* dr = data + (size_t)s * 64;
        dr[jlane]      = v0 * sc;
        dr[16 + jlane] = v1 * sc;
        dr[32 + jlane] = v2 * sc;
        if (jlane == 0) {
          dr[48] = Y[0]; dr[49] = Y[1]; dr[50] = Y[2];
          dr[51] = Y[3]; dr[52] = Y[4]; dr[53] = Y[5];
          dr[54] = Y[6]; dr[55] = Y[7]; dr[56] = Y[8];
        }
      }
      __syncthreads();
    }
    __syncthreads();
  }
}

// ---------------- gather kernel (phase 2) ----------------
__global__ __launch_bounds__(256)
void gather_kernel(const float* __restrict__ data,
                   const int* __restrict__ head,
                   const int* __restrict__ next,
                   float* __restrict__ out, int N)
{
  int gid = blockIdx.x * 256 + threadIdx.x;
  int node = gid >> 4;
  int h = gid & 15;
  if (node >= N) return;

  float a0 = 0.f;
  float a10 = 0.f, a11 = 0.f, a12 = 0.f;
  float a20 = 0.f, a21 = 0.f, a22 = 0.f, a23 = 0.f, a24 = 0.f;

  int p = head[node];
  while (p >= 0) {
    const float* dr = data + (size_t)p * 64;
    float v0 = dr[h], v1 = dr[16 + h], v2 = dr[32 + h];
    float y0 = dr[48], y1 = dr[49], y2 = dr[50], y3 = dr[51];
    float y4 = dr[52], y5 = dr[53], y6 = dr[54], y7 = dr[55], y8 = dr[56];
    a0  = fmaf(v0, y0, a0);
    a10 = fmaf(v1, y1, a10);
    a11 = fmaf(v1, y2, a11);
    a12 = fmaf(v1, y3, a12);
    a20 = fmaf(v2, y4, a20);
    a21 = fmaf(v2, y5, a21);
    a22 = fmaf(v2, y6, a22);
    a23 = fmaf(v2, y7, a23);
    a24 = fmaf(v2, y8, a24);
    p = next[p];
  }

  float* o = out + (size_t)node * 144;
  o[h] = a0;
  o[16 + h*3 + 0] = a10;
  o[16 + h*3 + 1] = a11;
  o[16 + h*3 + 2] = a12;
  o[64 + h*5 + 0] = a20;
  o[64 + h*5 + 1] = a21;
  o[64 + h*5 + 2] = a22;
  o[64 + h*5 + 3] = a23;
  o[64 + h*5 + 4] = a24;
}

// ---------------- fallback (R1): direct atomics ----------------
__global__ __launch_bounds__(256, 2)
void interact_atomic_kernel(const float* __restrict__ xfeat,
                            const float* __restrict__ coords,
                            const int* __restrict__ eidx,
                            const float* __restrict__ W1g,
                            const float* __restrict__ W2g,
                            float* __restrict__ out,
                            int E, int ntiles)
{
  __shared__ float W2s[768 * W2S];
  __shared__ float W1s[256];
  __shared__ float xss[16][16];
  __shared__ float hss[16][16];
  __shared__ unsigned char clist[256];
  __shared__ int wsum[4];

  const int tid = threadIdx.x;
  W1s[tid] = W1g[tid];
  for (int t = tid; t < 12288; t += 256) {
    int k = t / 768;
    int r = t - k * 768;
    int l = r >> 8;
    int rc = r & 255;
    int c = rc >> 4;
    int h = rc & 15;
    W2s[((k * 3 + l) * 16 + h) * W2S + c] = W2g[t];
  }
  __syncthreads();

  const int slot  = tid >> 4;
  const int jlane = tid & 15;
  const int wid   = tid >> 6;
  const int lane  = tid & 63;

  for (int tile = blockIdx.x; tile < ntiles; tile += gridDim.x) {
    const int ebase = tile * 256;
    int e = ebase + tid;
    bool act = false;
    if (e < E) {
      int s = eidx[e], d = eidx[E + e];
      float rx = coords[3*s]   - coords[3*d];
      float ry = coords[3*s+1] - coords[3*d+1];
      float rz = coords[3*s+2] - coords[3*d+2];
      float d2 = rx*rx + ry*ry + rz*rz;
      act = (d2 > 0.0f) && (d2 < 36.0f);
    }
    unsigned long long bm = __ballot(act);
    int pfx = __popcll(bm & ((1ull << lane) - 1ull));
    if (lane == 0) wsum[wid] = __popcll(bm);
    __syncthreads();
    int base = 0;
    #pragma unroll
    for (int w = 0; w < 4; w++) base += (w < wid) ? wsum[w] : 0;
    const int total = wsum[0] + wsum[1] + wsum[2] + wsum[3];
    if (act) clist[base + pfx] = (unsigned char)tid;
    __syncthreads();

    for (int s0 = 0; s0 < total; s0 += 16) {
      const int ci = s0 + slot;
      const bool on = ci < total;
      int dst = 0;
      float Y[9];
      if (on) {
        const int ee  = ebase + (int)clist[ci];
        const int src = eidx[ee];
        dst = eidx[E + ee];
        float rx = coords[3*src]   - coords[3*dst];
        float ry = coords[3*src+1] - coords[3*dst+1];
        float rz = coords[3*src+2] - coords[3*dst+2];
        float dd  = sqrtf(rx*rx + ry*ry + rz*rz);
        float inv = 1.0f / dd;
        float x = rx*inv, y = ry*inv, z = rz*inv;
        const float A0 = 0.28209479177387814f;
        const float A1 = 0.48860251190291992f;
        const float A2 = 1.09254843059207907f;
        const float A3 = 0.63078313050504001f;
        Y[0] = A0;
        Y[1] = A1*x;   Y[2] = A1*y;   Y[3] = A1*z;
        Y[4] = A2*x*z; Y[5] = A2*x*y;
        Y[6] = A3*(y*y - 0.5f*(x*x + z*z));
        Y[7] = A2*y*z;
        Y[8] = 0.5f*A2*(z*z - x*x);
        float theta = 0.52359877559829887f * dd;
        float s1 = __sinf(theta), c1 = __cosf(theta);
        float snm = 0.0f, sn = s1, bsum = 0.0f;
        #pragma unroll
        for (int k = 0; k < 16; k++) {
          bsum = fmaf(sn, W1s[k*16 + jlane], bsum);
          float sp = 2.0f*c1*sn - snm;
          snm = sn; sn = sp;
        }
        float p  = bsum * (2.30940107675850305f * inv) * 0.25f;
        float hv = 1.679177f * p / (1.0f + __expf(-p));
        hss[slot][jlane] = hv;
        xss[slot][jlane] = xfeat[src*16 + jlane];
      }
      __syncthreads();
      if (on) {
        float acc[3][16];
        #pragma unroll
        for (int l = 0; l < 3; l++)
          #pragma unroll
          for (int c = 0; c < 16; c++) acc[l][c] = 0.0f;
        #pragma unroll
        for (int k = 0; k < 16; k++) {
          const float hk = hss[slot][k];
          #pragma unroll
          for (int l = 0; l < 3; l++) {
            const float* wr = &W2s[((k*3 + l)*16 + jlane) * W2S];
            #pragma unroll
            for (int c = 0; c < 16; c++)
              acc[l][c] = fmaf(hk, wr[c], acc[l][c]);
          }
        }
        float v0 = 0.f, v1 = 0.f, v2 = 0.f;
        #pragma unroll
        for (int c = 0; c < 16; c++) {
          const float xc = xss[slot][c];
          v0 = fmaf(xc, acc[0][c], v0);
          v1 = fmaf(xc, acc[1][c], v1);
          v2 = fmaf(xc, acc[2][c], v2);
        }
        const float sc = 0.00390625f;
        v0 *= sc; v1 *= sc; v2 *= sc;
        float* o = out + (size_t)dst * 144;
        atomicAdd(o + jlane, v0 * Y[0]);
        #pragma unroll
        for (int mm = 0; mm < 3; mm++)
          atomicAdd(o + 16 + jlane*3 + mm, v1 * Y[1 + mm]);
        #pragma unroll
        for (int mm = 0; mm < 5; mm++)
          atomicAdd(o + 64 + jlane*5 + mm, v2 * Y[4 + mm]);
      }
      __syncthreads();
    }
    __syncthreads();
  }
}

extern "C" void kernel_launch(void* const* d_in, const int* in_sizes, int n_in,
                              void* d_out, int out_size, void* d_ws, size_t ws_size,
                              hipStream_t stream) {
  const float* xfeat  = (const float*)d_in[0];
  const float* coords = (const float*)d_in[1];
  const int*   eidx   = (const int*)d_in[2];
  const float* W1     = (const float*)d_in[3];
  const float* W2     = (const float*)d_in[4];
  float* out = (float*)d_out;

  const int E = in_sizes[2] / 2;
  const int N = out_size / 144;
  const int ntiles = (E + 255) / 256;
  const int nblk = ntiles < 4096 ? ntiles : 4096;

  // ws layout: data[E*64 f32] | head[N int] | next[E int] | ctr[pad to 64B]
  size_t off_data = 0;
  size_t off_head = off_data + (size_t)E * 64 * sizeof(float);
  size_t off_next = off_head + (size_t)N * sizeof(int);
  size_t off_ctr  = off_next + (size_t)E * sizeof(int);
  size_t need     = off_ctr + 64;

  if (ws_size >= need) {
    char* ws = (char*)d_ws;
    float* data = (float*)(ws + off_data);
    int*   head = (int*)(ws + off_head);
    int*   next = (int*)(ws + off_next);
    int*   ctr  = (int*)(ws + off_ctr);

    hipMemsetAsync(head, 0xFF, (size_t)N * sizeof(int), stream);  // -1
    hipMemsetAsync(ctr, 0, sizeof(int), stream);

    interact_kernel<<<nblk, 256, 0, stream>>>(xfeat, coords, eidx, W1, W2,
                                              data, head, next, ctr, E, ntiles);
    int gblk = (N * 16 + 255) / 256;
    gather_kernel<<<gblk, 256, 0, stream>>>(data, head, next, out, N);
  } else {
    hipMemsetAsync(d_out, 0, (size_t)out_size * sizeof(float), stream);
    interact_atomic_kernel<<<nblk, 256, 0, stream>>>(xfeat, coords, eidx, W1, W2,
                                                     out, E, ntiles);
  }
}

// Round 3
// 38.214 us; speedup vs baseline: 6.2319x; 6.2319x over previous
//
#include <hip/hip_runtime.h>
#include <math.h>

// InteractionBlock R3: MFMA GEMM for the per-edge weight contraction.
//   v[e, l*16+h] = sum_{kk,c} hvec[e,kk] * xs[e,c] * W2[kk,l,c,h]
//                = ( q[e,:] @ W2r )  with q[e, kk*16+c] = hvec[e,kk]*xs[e,c]
//   -> GEMM [E,256]x[256,48] via mfma_f32_16x16x32_bf16, B-frags in VGPRs.
// Two-phase scatter (linked list per dst, bf16 factored messages), no output atomics.

typedef __attribute__((ext_vector_type(8))) short short8;
typedef __attribute__((ext_vector_type(4))) float f32x4;

static __device__ __forceinline__ unsigned short f2bf(float f) {
  unsigned u = __builtin_bit_cast(unsigned, f);
  u = (u + 0x7FFFu + ((u >> 16) & 1u)) >> 16;
  return (unsigned short)u;
}
static __device__ __forceinline__ float bf2f(unsigned short s) {
  unsigned u = ((unsigned)s) << 16;
  return __builtin_bit_cast(float, u);
}

// ---- pre-kernel: pack W2 into pre-swizzled bf16 MFMA B-fragments ----
// frag fi = s*3+t (s=k-step 0..7, t=n-tile 0..2); entry (fi,lane,j):
//   k_global = s*32 + (lane>>4)*8 + j, n = t*16 + (lane&15)
//   W2r[k][n] = W2[kk*768 + t*256 + c*16 + h], kk=k>>4, c=k&15, h=lane&15
__global__ void w2f_build(const float* __restrict__ W2, unsigned short* __restrict__ w2f) {
  int gid = blockIdx.x * 256 + threadIdx.x;
  if (gid >= 24 * 64) return;
  int fi = gid >> 6, lane = gid & 63;
  int s = fi / 3, t = fi - 3 * s;
  int h = lane & 15, kq = lane >> 4;
  short8 pack;
  #pragma unroll
  for (int j = 0; j < 8; ++j) {
    int kg = s * 32 + kq * 8 + j;
    int kk = kg >> 4, c = kg & 15;
    pack[j] = (short)f2bf(W2[kk * 768 + t * 256 + c * 16 + h]);
  }
  *(short8*)&w2f[(size_t)gid * 8] = pack;
}

// ---- K1: per-edge features + compaction + MFMA GEMM + factored-message write ----
__global__ __launch_bounds__(256, 2)
void interact_kernel(const float* __restrict__ xfeat,
                     const float* __restrict__ coords,
                     const int* __restrict__ eidx,
                     const float* __restrict__ W1g,
                     const unsigned short* __restrict__ w2f,
                     unsigned short* __restrict__ data,  // [E][64] bf16
                     int* __restrict__ head,             // [N] init -1
                     int* __restrict__ next,             // [E]
                     int E)
{
  __shared__ float W1s[256];
  __shared__ float hsS[256 * 20];                       // stride 20 f32 (80B)
  __shared__ __align__(16) unsigned short xsS[256 * 24];// stride 24 ush (48B)
  __shared__ int eS[256];
  __shared__ int wsum[4];

  const int tid  = threadIdx.x;
  const int lane = tid & 63, wid = tid >> 6;
  W1s[tid] = W1g[tid];

  const int e = blockIdx.x * 256 + tid;
  bool act = false;
  int src = 0, dst = 0;
  float rx = 0.f, ry = 0.f, rz = 0.f, d2 = 0.f;
  if (e < E) {
    src = eidx[e]; dst = eidx[E + e];
    rx = coords[3*src]   - coords[3*dst];
    ry = coords[3*src+1] - coords[3*dst+1];
    rz = coords[3*src+2] - coords[3*dst+2];
    d2 = rx*rx + ry*ry + rz*rz;
    act = (d2 > 0.0f) && (d2 < 36.0f);
  }
  unsigned long long bm = __ballot(act);
  int pfx = __popcll(bm & ((1ull << lane) - 1ull));
  if (lane == 0) wsum[wid] = __popcll(bm);
  __syncthreads();                                   // covers W1s + wsum
  int base = 0;
  #pragma unroll
  for (int w = 0; w < 4; ++w) base += (w < wid) ? wsum[w] : 0;
  const int total = wsum[0] + wsum[1] + wsum[2] + wsum[3];
  const int cpos = base + pfx;

  if (act) {
    float dd  = sqrtf(d2);
    float inv = 1.0f / dd;
    float x = rx*inv, y = ry*inv, z = rz*inv;
    const float A0 = 0.28209479177387814f;  // 1/sqrt(4pi)
    const float A1 = 0.48860251190291992f;
    const float A2 = 1.09254843059207907f;
    const float A3 = 0.63078313050504001f;
    unsigned short* dr = data + (size_t)e * 64;
    dr[48] = f2bf(A0);
    dr[49] = f2bf(A1*x);   dr[50] = f2bf(A1*y);   dr[51] = f2bf(A1*z);
    dr[52] = f2bf(A2*x*z); dr[53] = f2bf(A2*x*y);
    dr[54] = f2bf(A3*(y*y - 0.5f*(x*x + z*z)));
    dr[55] = f2bf(A2*y*z);
    dr[56] = f2bf(0.5f*A2*(z*z - x*x));
    next[e] = atomicExch(&head[dst], e);

    // bessel -> hidden: h[j] = gain*silu( (eb@W1)[j]/4 )
    float theta = 0.52359877559829887f * dd;   // pi/6 * d
    float s1 = __sinf(theta), c1 = __cosf(theta);
    float snm = 0.0f, sn = s1;
    float hb[16];
    #pragma unroll
    for (int j = 0; j < 16; ++j) hb[j] = 0.0f;
    #pragma unroll
    for (int k = 0; k < 16; ++k) {
      #pragma unroll
      for (int j = 0; j < 16; ++j) hb[j] = fmaf(sn, W1s[k*16 + j], hb[j]);
      float sp = 2.0f*c1*sn - snm;
      snm = sn; sn = sp;
    }
    const float scale1 = 2.30940107675850305f * inv * 0.25f;
    float* hrow = &hsS[cpos * 20];
    #pragma unroll
    for (int j = 0; j < 16; ++j) {
      float p = hb[j] * scale1;
      hrow[j] = 1.679177f * p / (1.0f + __expf(-p));
    }
    unsigned short* xrow = &xsS[cpos * 24];
    #pragma unroll
    for (int cc = 0; cc < 4; ++cc) {
      float4 xv = *(const float4*)&xfeat[src*16 + cc*4];
      xrow[cc*4+0] = f2bf(xv.x); xrow[cc*4+1] = f2bf(xv.y);
      xrow[cc*4+2] = f2bf(xv.z); xrow[cc*4+3] = f2bf(xv.w);
    }
    eS[cpos] = e;
  }
  const int padded = (total + 15) & ~15;
  if (tid >= total && tid < padded) {       // zero pad rows (avoid NaN poison)
    #pragma unroll
    for (int j = 0; j < 16; ++j) hsS[tid*20 + j] = 0.0f;
    #pragma unroll
    for (int j = 0; j < 16; ++j) xsS[tid*24 + j] = 0;
  }
  __syncthreads();

  // ---- phase B: GEMM [padded,256] x [256,48] ----
  short8 bfr[8][3];
  #pragma unroll
  for (int s = 0; s < 8; ++s)
    #pragma unroll
    for (int t = 0; t < 3; ++t)
      bfr[s][t] = *(const short8*)&w2f[(size_t)((s*3 + t)*64 + lane) * 8];

  const int ngroups = padded >> 4;
  const int ma = lane & 15, kq = lane >> 4;
  const int c0 = (kq & 1) * 8;
  for (int g = wid; g < ngroups; g += 4) {
    const int cidx = g*16 + ma;
    const float* hrow = &hsS[cidx * 20];
    const unsigned short* xrow = &xsS[cidx * 24];
    float xsf[8];
    #pragma unroll
    for (int j = 0; j < 8; ++j) xsf[j] = bf2f(xrow[c0 + j]);

    f32x4 acc0 = {0,0,0,0}, acc1 = {0,0,0,0}, acc2 = {0,0,0,0};
    #pragma unroll
    for (int s = 0; s < 8; ++s) {
      const float hk = hrow[2*s + (kq >> 1)];
      short8 a;
      #pragma unroll
      for (int j = 0; j < 8; ++j) a[j] = (short)f2bf(hk * xsf[j]);
      acc0 = __builtin_amdgcn_mfma_f32_16x16x32_bf16(a, bfr[s][0], acc0, 0, 0, 0);
      acc1 = __builtin_amdgcn_mfma_f32_16x16x32_bf16(a, bfr[s][1], acc1, 0, 0, 0);
      acc2 = __builtin_amdgcn_mfma_f32_16x16x32_bf16(a, bfr[s][2], acc2, 0, 0, 0);
    }
    // D layout: row = kq*4 + r, col = lane&15  (m89-verified)
    const float sc = 0.00390625f;  // 1/256
    #pragma unroll
    for (int r = 0; r < 4; ++r) {
      const int cr = g*16 + kq*4 + r;
      if (cr < total) {
        unsigned short* dr = data + (size_t)eS[cr] * 64;
        dr[ 0 + ma] = f2bf(acc0[r] * sc);
        dr[16 + ma] = f2bf(acc1[r] * sc);
        dr[32 + ma] = f2bf(acc2[r] * sc);
      }
    }
  }
}

// ---- K2: gather (16 threads per node walk the dst list) ----
__global__ __launch_bounds__(256)
void gather_kernel(const unsigned short* __restrict__ data,
                   const int* __restrict__ head,
                   const int* __restrict__ next,
                   float* __restrict__ out, int N)
{
  int gid = blockIdx.x * 256 + threadIdx.x;
  int node = gid >> 4, h = gid & 15;
  if (node >= N) return;

  float a0 = 0.f;
  float a10 = 0.f, a11 = 0.f, a12 = 0.f;
  float a20 = 0.f, a21 = 0.f, a22 = 0.f, a23 = 0.f, a24 = 0.f;

  int p = head[node];
  while (p >= 0) {
    const unsigned short* dr = data + (size_t)p * 64;
    float v0 = bf2f(dr[h]), v1 = bf2f(dr[16 + h]), v2 = bf2f(dr[32 + h]);
    a0  = fmaf(v0, bf2f(dr[48]), a0);
    a10 = fmaf(v1, bf2f(dr[49]), a10);
    a11 = fmaf(v1, bf2f(dr[50]), a11);
    a12 = fmaf(v1, bf2f(dr[51]), a12);
    a20 = fmaf(v2, bf2f(dr[52]), a20);
    a21 = fmaf(v2, bf2f(dr[53]), a21);
    a22 = fmaf(v2, bf2f(dr[54]), a22);
    a23 = fmaf(v2, bf2f(dr[55]), a23);
    a24 = fmaf(v2, bf2f(dr[56]), a24);
    p = next[p];
  }

  float* o = out + (size_t)node * 144;
  o[h] = a0;
  o[16 + h*3 + 0] = a10;
  o[16 + h*3 + 1] = a11;
  o[16 + h*3 + 2] = a12;
  o[64 + h*5 + 0] = a20;
  o[64 + h*5 + 1] = a21;
  o[64 + h*5 + 2] = a22;
  o[64 + h*5 + 3] = a23;
  o[64 + h*5 + 4] = a24;
}

extern "C" void kernel_launch(void* const* d_in, const int* in_sizes, int n_in,
                              void* d_out, int out_size, void* d_ws, size_t ws_size,
                              hipStream_t stream) {
  const float* xfeat  = (const float*)d_in[0];
  const float* coords = (const float*)d_in[1];
  const int*   eidx   = (const int*)d_in[2];
  const float* W1     = (const float*)d_in[3];
  const float* W2     = (const float*)d_in[4];
  float* out = (float*)d_out;

  const int E = in_sizes[2] / 2;
  const int N = out_size / 144;

  // ws layout (16B-aligned chunks): data bf16[E][64] | head[N] | next[E] | w2f[12288 ush]
  char* ws = (char*)d_ws;
  size_t off_head = (size_t)E * 64 * sizeof(unsigned short);
  size_t off_next = off_head + (size_t)N * sizeof(int);
  size_t off_w2f  = off_next + (size_t)E * sizeof(int);
  unsigned short* data = (unsigned short*)ws;
  int* head = (int*)(ws + off_head);
  int* next = (int*)(ws + off_next);
  unsigned short* w2f = (unsigned short*)(ws + off_w2f);

  hipMemsetAsync(head, 0xFF, (size_t)N * sizeof(int), stream);  // head = -1

  w2f_build<<<6, 256, 0, stream>>>(W2, w2f);
  interact_kernel<<<(E + 255) / 256, 256, 0, stream>>>(xfeat, coords, eidx, W1,
                                                       w2f, data, head, next, E);
  gather_kernel<<<(N * 16 + 255) / 256, 256, 0, stream>>>(data, head, next, out, N);
}

// Round 4
// 37.442 us; speedup vs baseline: 6.3605x; 1.0206x over previous
//
#include <hip/hip_runtime.h>
#include <math.h>

// InteractionBlock R4.
//  prep:    head[]=-1  +  pack W2 into pre-swizzled bf16 MFMA B-fragments (one kernel).
//  K1:      per-edge geometry/bessel-MLP -> ballot compaction -> MFMA GEMM
//           [E,256](q = h (x) xs) x [256,48](W2 frags in VGPRs) -> factored bf16
//           message rows data[e] = { v[16][4], Y1..Y8 } (144B, Y0 is a constant).
//  K2:      per-node linked-list gather, expand msg = v_l[h]*Y[m], write out once.

typedef __attribute__((ext_vector_type(8))) short short8;
typedef __attribute__((ext_vector_type(4))) float f32x4;
typedef __attribute__((ext_vector_type(4))) unsigned short u16x4;

#define DSTRIDE 72  // ushorts per data row (144 B, 16B-aligned)

static __device__ __forceinline__ unsigned short f2bf(float f) {
  unsigned u = __builtin_bit_cast(unsigned, f);
  u = (u + 0x7FFFu + ((u >> 16) & 1u)) >> 16;
  return (unsigned short)u;
}
static __device__ __forceinline__ float bf2f(unsigned short s) {
  unsigned u = ((unsigned)s) << 16;
  return __builtin_bit_cast(float, u);
}

// ---- prep: head init + W2 -> bf16 B-fragments ----
// frag fi = s*3+t (s=k-step 0..7, t=n-tile 0..2); entry (fi,lane,j):
//   k_global = s*32 + (lane>>4)*8 + j, n = t*16 + (lane&15)
//   W2r[k][n] = W2[kk*768 + t*256 + c*16 + h], kk=k>>4, c=k&15, h=lane&15
__global__ __launch_bounds__(256)
void prep_kernel(const float* __restrict__ W2, unsigned short* __restrict__ w2f,
                 int* __restrict__ head, int N) {
  int gid = blockIdx.x * 256 + threadIdx.x;
  if (gid < N) head[gid] = -1;
  if (gid < 24 * 64) {
    int fi = gid >> 6, lane = gid & 63;
    int s = fi / 3, t = fi - 3 * s;
    int h = lane & 15, kq = lane >> 4;
    short8 pack;
    #pragma unroll
    for (int j = 0; j < 8; ++j) {
      int kg = s * 32 + kq * 8 + j;
      int kk = kg >> 4, c = kg & 15;
      pack[j] = (short)f2bf(W2[kk * 768 + t * 256 + c * 16 + h]);
    }
    *(short8*)&w2f[(size_t)gid * 8] = pack;
  }
}

// ---- K1: per-edge features + compaction + MFMA GEMM + factored-message write ----
__global__ __launch_bounds__(256, 3)
void interact_kernel(const float* __restrict__ xfeat,
                     const float* __restrict__ coords,
                     const int* __restrict__ eidx,
                     const float* __restrict__ W1g,
                     const unsigned short* __restrict__ w2f,
                     unsigned short* __restrict__ data,  // [E][72] bf16
                     int* __restrict__ head,             // [N] init -1
                     int* __restrict__ next,             // [E]
                     int E)
{
  __shared__ float W1s[256];
  __shared__ float hsS[256 * 20];                        // stride 20 f32 (80B)
  __shared__ __align__(16) unsigned short xsS[256 * 24]; // stride 24 ush (48B)
  __shared__ int eS[256];
  __shared__ int wsum[4];

  const int tid  = threadIdx.x;
  const int lane = tid & 63, wid = tid >> 6;
  W1s[tid] = W1g[tid];

  const int e = blockIdx.x * 256 + tid;
  bool act = false;
  int src = 0, dst = 0;
  float rx = 0.f, ry = 0.f, rz = 0.f, d2 = 0.f;
  if (e < E) {
    src = eidx[e]; dst = eidx[E + e];
    rx = coords[3*src]   - coords[3*dst];
    ry = coords[3*src+1] - coords[3*dst+1];
    rz = coords[3*src+2] - coords[3*dst+2];
    d2 = rx*rx + ry*ry + rz*rz;
    act = (d2 > 0.0f) && (d2 < 36.0f);
  }
  unsigned long long bm = __ballot(act);
  int pfx = __popcll(bm & ((1ull << lane) - 1ull));
  if (lane == 0) wsum[wid] = __popcll(bm);
  __syncthreads();                                   // covers W1s + wsum
  int base = 0;
  #pragma unroll
  for (int w = 0; w < 4; ++w) base += (w < wid) ? wsum[w] : 0;
  const int total = wsum[0] + wsum[1] + wsum[2] + wsum[3];
  const int cpos = base + pfx;

  if (act) {
    float dd  = sqrtf(d2);
    float inv = 1.0f / dd;
    float x = rx*inv, y = ry*inv, z = rz*inv;
    const float A1 = 0.48860251190291992f;  // sqrt(3)/sqrt(4pi)
    const float A2 = 1.09254843059207907f;  // sqrt(15)/sqrt(4pi)
    const float A3 = 0.63078313050504001f;  // sqrt(5)/sqrt(4pi)
    unsigned short* dr = data + (size_t)e * DSTRIDE;
    short8 ys;
    ys[0] = (short)f2bf(A1*x);   ys[1] = (short)f2bf(A1*y);  ys[2] = (short)f2bf(A1*z);
    ys[3] = (short)f2bf(A2*x*z); ys[4] = (short)f2bf(A2*x*y);
    ys[5] = (short)f2bf(A3*(y*y - 0.5f*(x*x + z*z)));
    ys[6] = (short)f2bf(A2*y*z); ys[7] = (short)f2bf(0.5f*A2*(z*z - x*x));
    *(short8*)&dr[64] = ys;
    next[e] = atomicExch(&head[dst], e);

    // bessel -> hidden: h[j] = gain*silu( (eb@W1)[j]/4 )
    float theta = 0.52359877559829887f * dd;   // pi/6 * d
    float s1 = __sinf(theta), c1 = __cosf(theta);
    float snm = 0.0f, sn = s1;
    float hb[16];
    #pragma unroll
    for (int j = 0; j < 16; ++j) hb[j] = 0.0f;
    #pragma unroll
    for (int k = 0; k < 16; ++k) {
      #pragma unroll
      for (int j = 0; j < 16; ++j) hb[j] = fmaf(sn, W1s[k*16 + j], hb[j]);
      float sp = 2.0f*c1*sn - snm;
      snm = sn; sn = sp;
    }
    const float scale1 = 2.30940107675850305f * inv * 0.25f;
    float* hrow = &hsS[cpos * 20];
    #pragma unroll
    for (int j = 0; j < 16; ++j) {
      float p = hb[j] * scale1;
      hrow[j] = 1.679177f * p / (1.0f + __expf(-p));
    }
    unsigned short* xrow = &xsS[cpos * 24];
    #pragma unroll
    for (int cc = 0; cc < 4; ++cc) {
      float4 xv = *(const float4*)&xfeat[src*16 + cc*4];
      xrow[cc*4+0] = f2bf(xv.x); xrow[cc*4+1] = f2bf(xv.y);
      xrow[cc*4+2] = f2bf(xv.z); xrow[cc*4+3] = f2bf(xv.w);
    }
    eS[cpos] = e;
  }
  const int padded = (total + 15) & ~15;
  if (tid >= total && tid < padded) {       // zero pad rows (avoid NaN poison)
    #pragma unroll
    for (int j = 0; j < 16; ++j) hsS[tid*20 + j] = 0.0f;
    #pragma unroll
    for (int j = 0; j < 16; ++j) xsS[tid*24 + j] = 0;
  }
  __syncthreads();

  // ---- phase B: GEMM [padded,256] x [256,48] ----
  short8 bfr[8][3];
  #pragma unroll
  for (int s = 0; s < 8; ++s)
    #pragma unroll
    for (int t = 0; t < 3; ++t)
      bfr[s][t] = *(const short8*)&w2f[(size_t)((s*3 + t)*64 + lane) * 8];

  const int ngroups = padded >> 4;
  const int ma = lane & 15, kq = lane >> 4;
  const int c0 = (kq & 1) * 8;
  for (int g = wid; g < ngroups; g += 4) {
    const int cidx = g*16 + ma;
    const float* hrow = &hsS[cidx * 20];
    const unsigned short* xrow = &xsS[cidx * 24];
    float xsf[8];
    #pragma unroll
    for (int j = 0; j < 8; ++j) xsf[j] = bf2f(xrow[c0 + j]);

    f32x4 acc0 = {0,0,0,0}, acc1 = {0,0,0,0}, acc2 = {0,0,0,0};
    #pragma unroll
    for (int s = 0; s < 8; ++s) {
      const float hk = hrow[2*s + (kq >> 1)];
      short8 a;
      #pragma unroll
      for (int j = 0; j < 8; ++j) a[j] = (short)f2bf(hk * xsf[j]);
      acc0 = __builtin_amdgcn_mfma_f32_16x16x32_bf16(a, bfr[s][0], acc0, 0, 0, 0);
      acc1 = __builtin_amdgcn_mfma_f32_16x16x32_bf16(a, bfr[s][1], acc1, 0, 0, 0);
      acc2 = __builtin_amdgcn_mfma_f32_16x16x32_bf16(a, bfr[s][2], acc2, 0, 0, 0);
    }
    // D layout: row = kq*4 + r, col = lane&15  (m89-verified)
    const float sc = 0.00390625f;  // 1/256
    #pragma unroll
    for (int r = 0; r < 4; ++r) {
      const int cr = g*16 + kq*4 + r;
      if (cr < total) {
        unsigned short* dr = data + (size_t)eS[cr] * DSTRIDE;
        u16x4 vv;
        vv[0] = f2bf(acc0[r] * sc);
        vv[1] = f2bf(acc1[r] * sc);
        vv[2] = f2bf(acc2[r] * sc);
        vv[3] = 0;
        *(u16x4*)&dr[ma * 4] = vv;
      }
    }
  }
}

// ---- K2: gather (16 threads per node walk the dst list) ----
__global__ __launch_bounds__(256)
void gather_kernel(const unsigned short* __restrict__ data,
                   const int* __restrict__ head,
                   const int* __restrict__ next,
                   float* __restrict__ out, int N)
{
  int gid = blockIdx.x * 256 + threadIdx.x;
  int node = gid >> 4, h = gid & 15;
  if (node >= N) return;

  float a0 = 0.f;
  float a10 = 0.f, a11 = 0.f, a12 = 0.f;
  float a20 = 0.f, a21 = 0.f, a22 = 0.f, a23 = 0.f, a24 = 0.f;

  int p = head[node];
  while (p >= 0) {
    const unsigned short* dr = data + (size_t)p * DSTRIDE;
    int pn = next[p];
    u16x4 vv = *(const u16x4*)&dr[h * 4];
    short8 yv = *(const short8*)&dr[64];
    float v0 = bf2f(vv[0]), v1 = bf2f(vv[1]), v2 = bf2f(vv[2]);
    a0  += v0;
    a10 = fmaf(v1, bf2f((unsigned short)yv[0]), a10);
    a11 = fmaf(v1, bf2f((unsigned short)yv[1]), a11);
    a12 = fmaf(v1, bf2f((unsigned short)yv[2]), a12);
    a20 = fmaf(v2, bf2f((unsigned short)yv[3]), a20);
    a21 = fmaf(v2, bf2f((unsigned short)yv[4]), a21);
    a22 = fmaf(v2, bf2f((unsigned short)yv[5]), a22);
    a23 = fmaf(v2, bf2f((unsigned short)yv[6]), a23);
    a24 = fmaf(v2, bf2f((unsigned short)yv[7]), a24);
    p = pn;
  }

  float* o = out + (size_t)node * 144;
  o[h] = a0 * 0.28209479177387814f;   // Y0 is constant: fold at the end
  o[16 + h*3 + 0] = a10;
  o[16 + h*3 + 1] = a11;
  o[16 + h*3 + 2] = a12;
  o[64 + h*5 + 0] = a20;
  o[64 + h*5 + 1] = a21;
  o[64 + h*5 + 2] = a22;
  o[64 + h*5 + 3] = a23;
  o[64 + h*5 + 4] = a24;
}

extern "C" void kernel_launch(void* const* d_in, const int* in_sizes, int n_in,
                              void* d_out, int out_size, void* d_ws, size_t ws_size,
                              hipStream_t stream) {
  const float* xfeat  = (const float*)d_in[0];
  const float* coords = (const float*)d_in[1];
  const int*   eidx   = (const int*)d_in[2];
  const float* W1     = (const float*)d_in[3];
  const float* W2     = (const float*)d_in[4];
  float* out = (float*)d_out;

  const int E = in_sizes[2] / 2;
  const int N = out_size / 144;

  // ws layout (all 16B-aligned): data bf16[E][72] | head[N] | next[E] | w2f[12288 ush]
  char* ws = (char*)d_ws;
  size_t off_head = (size_t)E * DSTRIDE * sizeof(unsigned short);
  size_t off_next = off_head + (size_t)((N + 3) & ~3) * sizeof(int);
  size_t off_w2f  = off_next + (size_t)E * sizeof(int);
  unsigned short* data = (unsigned short*)ws;
  int* head = (int*)(ws + off_head);
  int* next = (int*)(ws + off_next);
  unsigned short* w2f = (unsigned short*)(ws + off_w2f);

  int pblk = (N + 255) / 256;
  if (pblk < 6) pblk = 6;
  prep_kernel<<<pblk, 256, 0, stream>>>(W2, w2f, head, N);
  interact_kernel<<<(E + 255) / 256, 256, 0, stream>>>(xfeat, coords, eidx, W1,
                                                       w2f, data, head, next, E);
  gather_kernel<<<(N * 16 + 255) / 256, 256, 0, stream>>>(data, head, next, out, N);
}